// Round 4
// baseline (3880.433 us; speedup 1.0000x reference)
//
#include <hip/hip_runtime.h>
#include <hip/hip_cooperative_groups.h>

namespace cg = cooperative_groups;

#define NA 8192
#define NB 8192
#define N_LAYERS 16
#define NBLK 512                       // 2 blocks/CU on 256 CUs
#define NTHR 256
#define ROWS_PER_VC 64                 // rows per v-partial chunk
#define N_VC (NA / ROWS_PER_VC)        // 128 row-chunks x 4 col-chunks = 512

typedef _Float16 half_t;
typedef _Float16 half8_t __attribute__((ext_vector_type(8)));
typedef float float4_t __attribute__((ext_vector_type(4)));

__device__ __forceinline__ float dot8(half8_t e, float4_t w0, float4_t w1) {
    return ((float)e[0] * w0.x + (float)e[1] * w0.y) +
           ((float)e[2] * w0.z + (float)e[3] * w0.w) +
           ((float)e[4] * w1.x + (float)e[5] * w1.y) +
           ((float)e[6] * w1.z + (float)e[7] * w1.w);
}

__device__ __forceinline__ float wave_sum(float a) {
#pragma unroll
    for (int off = 32; off > 0; off >>= 1)
        a += __shfl_down(a, off, 64);
    return a;
}

// ---------------------------------------------------------------------------
// Whole Sinkhorn iteration in ONE cooperative kernel.
// 512 blocks x 256 threads, grid.sync() between phases.
// ---------------------------------------------------------------------------
__global__ __launch_bounds__(NTHR, 2) void sink_all(
    const float* __restrict__ C, const float* __restrict__ alpha,
    const float* __restrict__ beta, const float* __restrict__ d_eps,
    half_t* __restrict__ E, float* __restrict__ u, float* __restrict__ v,
    float* __restrict__ partial, float* __restrict__ out)
{
    cg::grid_group grid = cg::this_grid();
    const int b = blockIdx.x;
    const int t = threadIdx.x;
    const int wave = t >> 6;
    const int lane = t & 63;
    const float eps = d_eps[0];
    const float inv_eps = 1.0f / eps;

    __shared__ float sm[16][17];

    // ---- layer 0 u-phase: E = exp(-C/eps) (fp16), u0 = alpha/rowsum (v==1) --
    {
        const int r0 = b * 16 + wave * 4;           // 4 rows per wave
        const float4_t* C0 = (const float4_t*)(C + (size_t)(r0 + 0) * NB);
        const float4_t* C1 = (const float4_t*)(C + (size_t)(r0 + 1) * NB);
        const float4_t* C2 = (const float4_t*)(C + (size_t)(r0 + 2) * NB);
        const float4_t* C3 = (const float4_t*)(C + (size_t)(r0 + 3) * NB);
        half8_t* E0 = (half8_t*)(E + (size_t)(r0 + 0) * NB);
        half8_t* E1 = (half8_t*)(E + (size_t)(r0 + 1) * NB);
        half8_t* E2 = (half8_t*)(E + (size_t)(r0 + 2) * NB);
        half8_t* E3 = (half8_t*)(E + (size_t)(r0 + 3) * NB);
        float a0 = 0.f, a1 = 0.f, a2 = 0.f, a3 = 0.f;

#pragma unroll 2
        for (int k = 0; k < 16; ++k) {
            const int g = k * 64 + lane;            // half8 group, 1024/row
            {
                float4_t c0 = C0[2 * g], c1 = C0[2 * g + 1];
                half8_t h;
                float e0 = __expf(-c0.x * inv_eps), e1 = __expf(-c0.y * inv_eps);
                float e2 = __expf(-c0.z * inv_eps), e3 = __expf(-c0.w * inv_eps);
                float e4 = __expf(-c1.x * inv_eps), e5 = __expf(-c1.y * inv_eps);
                float e6 = __expf(-c1.z * inv_eps), e7 = __expf(-c1.w * inv_eps);
                h[0] = (_Float16)e0; h[1] = (_Float16)e1; h[2] = (_Float16)e2; h[3] = (_Float16)e3;
                h[4] = (_Float16)e4; h[5] = (_Float16)e5; h[6] = (_Float16)e6; h[7] = (_Float16)e7;
                E0[g] = h;
                a0 += ((e0 + e1) + (e2 + e3)) + ((e4 + e5) + (e6 + e7));
            }
            {
                float4_t c0 = C1[2 * g], c1 = C1[2 * g + 1];
                half8_t h;
                float e0 = __expf(-c0.x * inv_eps), e1 = __expf(-c0.y * inv_eps);
                float e2 = __expf(-c0.z * inv_eps), e3 = __expf(-c0.w * inv_eps);
                float e4 = __expf(-c1.x * inv_eps), e5 = __expf(-c1.y * inv_eps);
                float e6 = __expf(-c1.z * inv_eps), e7 = __expf(-c1.w * inv_eps);
                h[0] = (_Float16)e0; h[1] = (_Float16)e1; h[2] = (_Float16)e2; h[3] = (_Float16)e3;
                h[4] = (_Float16)e4; h[5] = (_Float16)e5; h[6] = (_Float16)e6; h[7] = (_Float16)e7;
                E1[g] = h;
                a1 += ((e0 + e1) + (e2 + e3)) + ((e4 + e5) + (e6 + e7));
            }
            {
                float4_t c0 = C2[2 * g], c1 = C2[2 * g + 1];
                half8_t h;
                float e0 = __expf(-c0.x * inv_eps), e1 = __expf(-c0.y * inv_eps);
                float e2 = __expf(-c0.z * inv_eps), e3 = __expf(-c0.w * inv_eps);
                float e4 = __expf(-c1.x * inv_eps), e5 = __expf(-c1.y * inv_eps);
                float e6 = __expf(-c1.z * inv_eps), e7 = __expf(-c1.w * inv_eps);
                h[0] = (_Float16)e0; h[1] = (_Float16)e1; h[2] = (_Float16)e2; h[3] = (_Float16)e3;
                h[4] = (_Float16)e4; h[5] = (_Float16)e5; h[6] = (_Float16)e6; h[7] = (_Float16)e7;
                E2[g] = h;
                a2 += ((e0 + e1) + (e2 + e3)) + ((e4 + e5) + (e6 + e7));
            }
            {
                float4_t c0 = C3[2 * g], c1 = C3[2 * g + 1];
                half8_t h;
                float e0 = __expf(-c0.x * inv_eps), e1 = __expf(-c0.y * inv_eps);
                float e2 = __expf(-c0.z * inv_eps), e3 = __expf(-c0.w * inv_eps);
                float e4 = __expf(-c1.x * inv_eps), e5 = __expf(-c1.y * inv_eps);
                float e6 = __expf(-c1.z * inv_eps), e7 = __expf(-c1.w * inv_eps);
                h[0] = (_Float16)e0; h[1] = (_Float16)e1; h[2] = (_Float16)e2; h[3] = (_Float16)e3;
                h[4] = (_Float16)e4; h[5] = (_Float16)e5; h[6] = (_Float16)e6; h[7] = (_Float16)e7;
                E3[g] = h;
                a3 += ((e0 + e1) + (e2 + e3)) + ((e4 + e5) + (e6 + e7));
            }
        }
        a0 = wave_sum(a0); a1 = wave_sum(a1); a2 = wave_sum(a2); a3 = wave_sum(a3);
        if (lane == 0) {
            u[r0 + 0] = alpha[r0 + 0] / a0;
            u[r0 + 1] = alpha[r0 + 1] / a1;
            u[r0 + 2] = alpha[r0 + 2] / a2;
            u[r0 + 3] = alpha[r0 + 3] / a3;
        }
    }
    grid.sync();

    for (int layer = 0; layer < N_LAYERS; ++layer) {
        // ---- v-partial: partial[rc][j] = sum_{i in chunk rc} E[i,j]*u[i] ----
        {
            const int cc = b & 3;                   // col-chunk 0..3
            const int rc = b >> 2;                  // row-chunk 0..127
            const int row0 = rc * ROWS_PER_VC;
            const int g = cc * 256 + t;             // half8 group, 1024/row
            const half8_t* Eb = (const half8_t*)E;

            float acc[8];
#pragma unroll
            for (int k = 0; k < 8; ++k) acc[k] = 0.0f;

#pragma unroll 8
            for (int r = 0; r < ROWS_PER_VC; ++r) {
                const float ur = u[row0 + r];
                half8_t e = Eb[(size_t)(row0 + r) * (NB / 8) + g];
#pragma unroll
                for (int k = 0; k < 8; ++k) acc[k] += ur * (float)e[k];
            }
            float4_t o0 = {acc[0], acc[1], acc[2], acc[3]};
            float4_t o1 = {acc[4], acc[5], acc[6], acc[7]};
            float4_t* p = (float4_t*)(partial + (size_t)rc * NB + (size_t)g * 8);
            p[0] = o0;
            p[1] = o1;
        }
        grid.sync();

        // ---- combine: v[j] = beta[j] / sum_rc partial[rc][j] ----
        {
            const int ci = t & 15;                  // col within block's 16
            const int grp = t >> 4;                 // 0..15, each sums 8 rcs
            const int col = b * 16 + ci;
            float s = 0.0f;
#pragma unroll
            for (int i = 0; i < 8; ++i)
                s += partial[(size_t)(grp * 8 + i) * NB + col];
            sm[ci][grp] = s;
            __syncthreads();
            if (grp == 0) {
                float tot = 0.0f;
#pragma unroll
                for (int i = 0; i < 16; ++i) tot += sm[ci][i];
                v[col] = beta[col] / tot;
            }
            __syncthreads();
        }
        grid.sync();

        if (layer == N_LAYERS - 1) break;

        // ---- u-phase: u[i] = alpha[i] / sum_j E[i,j]*v[j], 4 rows/wave ----
        {
            const int r0 = b * 16 + wave * 4;
            const half8_t* E0 = (const half8_t*)(E + (size_t)(r0 + 0) * NB);
            const half8_t* E1 = (const half8_t*)(E + (size_t)(r0 + 1) * NB);
            const half8_t* E2 = (const half8_t*)(E + (size_t)(r0 + 2) * NB);
            const half8_t* E3 = (const half8_t*)(E + (size_t)(r0 + 3) * NB);
            const float4_t* vv = (const float4_t*)v;
            float a0 = 0.f, a1 = 0.f, a2 = 0.f, a3 = 0.f;

#pragma unroll 4
            for (int k = 0; k < 16; ++k) {
                const int g = k * 64 + lane;
                float4_t w0 = vv[2 * g];
                float4_t w1 = vv[2 * g + 1];
                half8_t e0 = E0[g];
                half8_t e1 = E1[g];
                half8_t e2 = E2[g];
                half8_t e3 = E3[g];
                a0 += dot8(e0, w0, w1);
                a1 += dot8(e1, w0, w1);
                a2 += dot8(e2, w0, w1);
                a3 += dot8(e3, w0, w1);
            }
            a0 = wave_sum(a0); a1 = wave_sum(a1); a2 = wave_sum(a2); a3 = wave_sum(a3);
            if (lane == 0) {
                u[r0 + 0] = alpha[r0 + 0] / a0;
                u[r0 + 1] = alpha[r0 + 1] / a1;
                u[r0 + 2] = alpha[r0 + 2] / a2;
                u[r0 + 3] = alpha[r0 + 3] / a3;
            }
        }
        grid.sync();
    }

    // ---- finalize: out = [eps*log(u), eps*log(v)] ----
    {
        const int i = b * NTHR + t;
        if (i < NA) {
            out[i] = eps * __logf(u[i]);
        } else if (i < NA + NB) {
            out[i] = eps * __logf(v[i - NA]);
        }
    }
}

// ===========================================================================
// Fallback path (ws too small for E): round-3 style multi-kernel, fp32 C.
// ===========================================================================
__global__ __launch_bounds__(256) void fb_u_step(
    const float* __restrict__ C, const float* __restrict__ v,
    const float* __restrict__ alpha, const float* __restrict__ d_eps,
    float* __restrict__ u, int first)
{
    const int row = blockIdx.x;
    const int t = threadIdx.x;
    const float inv_eps = 1.0f / d_eps[0];
    const float4_t* Crow = (const float4_t*)(C + (size_t)row * NB);
    const float4_t* vv = (const float4_t*)v;
    float s = 0.0f;
#pragma unroll
    for (int k = 0; k < 8; ++k) {
        const int g = k * 256 + t;
        float4_t c = Crow[g];
        float4_t w = first ? float4_t{1.f, 1.f, 1.f, 1.f} : vv[g];
        s += __expf(-c.x * inv_eps) * w.x + __expf(-c.y * inv_eps) * w.y +
             __expf(-c.z * inv_eps) * w.z + __expf(-c.w * inv_eps) * w.w;
    }
    __shared__ float sm[256];
    sm[t] = s;
    __syncthreads();
    for (int off = 128; off > 0; off >>= 1) {
        if (t < off) sm[t] += sm[t + off];
        __syncthreads();
    }
    if (t == 0) u[row] = alpha[row] / sm[0];
}

__global__ __launch_bounds__(256) void fb_v_partial(
    const float* __restrict__ C, const float* __restrict__ u,
    const float* __restrict__ d_eps, float* __restrict__ partial)
{
    const int cc = blockIdx.x;
    const int rc = blockIdx.y;
    const int t = threadIdx.x;
    const int row0 = rc * ROWS_PER_VC;
    const float inv_eps = 1.0f / d_eps[0];
    const float4_t* Cb = (const float4_t*)C;
    const int g = (cc * 256 + t) * 2;
    float acc[8];
#pragma unroll
    for (int k = 0; k < 8; ++k) acc[k] = 0.0f;
#pragma unroll 4
    for (int r = 0; r < ROWS_PER_VC; ++r) {
        const float ur = u[row0 + r];
        float4_t c0 = Cb[(size_t)(row0 + r) * (NB / 4) + g];
        float4_t c1 = Cb[(size_t)(row0 + r) * (NB / 4) + g + 1];
        acc[0] += ur * __expf(-c0.x * inv_eps);
        acc[1] += ur * __expf(-c0.y * inv_eps);
        acc[2] += ur * __expf(-c0.z * inv_eps);
        acc[3] += ur * __expf(-c0.w * inv_eps);
        acc[4] += ur * __expf(-c1.x * inv_eps);
        acc[5] += ur * __expf(-c1.y * inv_eps);
        acc[6] += ur * __expf(-c1.z * inv_eps);
        acc[7] += ur * __expf(-c1.w * inv_eps);
    }
    float4_t o0 = {acc[0], acc[1], acc[2], acc[3]};
    float4_t o1 = {acc[4], acc[5], acc[6], acc[7]};
    float4_t* p = (float4_t*)(partial + (size_t)rc * NB + (size_t)(cc * 256 + t) * 8);
    p[0] = o0;
    p[1] = o1;
}

__global__ __launch_bounds__(256) void fb_v_combine(
    const float* __restrict__ partial, const float* __restrict__ beta,
    float* __restrict__ v)
{
    const int col = blockIdx.x * 256 + threadIdx.x;
    float s = 0.0f;
#pragma unroll 8
    for (int rc = 0; rc < N_VC; ++rc) s += partial[(size_t)rc * NB + col];
    v[col] = beta[col] / s;
}

__global__ __launch_bounds__(256) void fb_finalize(
    const float* __restrict__ u, const float* __restrict__ v,
    const float* __restrict__ d_eps, float* __restrict__ out)
{
    const int i = blockIdx.x * 256 + threadIdx.x;
    const float eps = d_eps[0];
    if (i < NA) out[i] = eps * logf(u[i]);
    else if (i < NA + NB) out[i] = eps * logf(v[i - NA]);
}

extern "C" void kernel_launch(void* const* d_in, const int* in_sizes, int n_in,
                              void* d_out, int out_size, void* d_ws, size_t ws_size,
                              hipStream_t stream)
{
    const float* alpha = (const float*)d_in[0];
    const float* beta  = (const float*)d_in[1];
    const float* C     = (const float*)d_in[2];
    const float* d_eps = (const float*)d_in[3];
    float* out = (float*)d_out;

    const size_t eBytes = (size_t)NA * NB * sizeof(half_t);   // 128 MiB
    const size_t pBytes = (size_t)N_VC * NB * sizeof(float);  // 4 MiB
    const size_t vecBytes = (size_t)NA * sizeof(float);       // 32 KiB

    char* ws = (char*)d_ws;
    const bool useE = ws_size >= eBytes + pBytes + 2 * vecBytes;

    if (useE) {
        half_t* E = (half_t*)ws;
        float* partial = (float*)(ws + eBytes);
        float* u = (float*)(ws + eBytes + pBytes);
        float* v = (float*)(ws + eBytes + pBytes + vecBytes);

        void* args[] = {(void*)&C, (void*)&alpha, (void*)&beta, (void*)&d_eps,
                        (void*)&E, (void*)&u, (void*)&v, (void*)&partial,
                        (void*)&out};
        hipLaunchCooperativeKernel((const void*)sink_all, dim3(NBLK), dim3(NTHR),
                                   args, 0, stream);
    } else {
        // fp32 fallback: needs only partial + u + v
        float* partial = (float*)ws;
        float* u = (float*)(ws + pBytes);
        float* v = (float*)(ws + pBytes + vecBytes);
        const dim3 blk(256);
        const dim3 gridRow(NA);
        const dim3 gridVP(NB / 2048, N_VC);
        for (int layer = 0; layer < N_LAYERS; ++layer) {
            fb_u_step<<<gridRow, blk, 0, stream>>>(C, v, alpha, d_eps, u,
                                                   layer == 0 ? 1 : 0);
            fb_v_partial<<<gridVP, blk, 0, stream>>>(C, u, d_eps, partial);
            fb_v_combine<<<dim3(NB / 256), blk, 0, stream>>>(partial, beta, v);
        }
        fb_finalize<<<dim3((NA + NB) / 256), blk, 0, stream>>>(u, v, d_eps, out);
    }
}

// Round 5
// 1242.831 us; speedup vs baseline: 3.1223x; 3.1223x over previous
//
#include <hip/hip_runtime.h>

#define NA 8192
#define NB 8192
#define N_LAYERS 16
#define RPC 16                  // rows per chunk (fused layer kernel)
#define N_CH (NA / RPC)         // 512 chunks = layer-kernel grid
#define FB_RPC 64               // fallback rows per chunk
#define FB_NCH (NA / FB_RPC)    // 128

typedef _Float16 half_t;
typedef _Float16 half8_t __attribute__((ext_vector_type(8)));
typedef float float4_t __attribute__((ext_vector_type(4)));

__device__ __forceinline__ float dot8(half8_t e, float4_t w0, float4_t w1) {
    return (((float)e[0] * w0.x + (float)e[1] * w0.y) +
            ((float)e[2] * w0.z + (float)e[3] * w0.w)) +
           (((float)e[4] * w1.x + (float)e[5] * w1.y) +
            ((float)e[6] * w1.z + (float)e[7] * w1.w));
}

__device__ __forceinline__ float wave_sum(float a) {
#pragma unroll
    for (int off = 32; off > 0; off >>= 1)
        a += __shfl_down(a, off, 64);
    return a;
}

// ---------------------------------------------------------------------------
// Fused layer: block owns RPC=16 rows.
//   phase A: u[i] = alpha[i] / sum_j E[i,j]*v[j]   (v in LDS; FIRST: v==1,
//            read C fp32, write E = exp(-C/eps) fp16)
//   phase B: partial[b][j] = sum_{i in chunk} E[i,j]*u[i]  (E re-read, L2/L3 hot)
// LAST also writes out[r] = eps*log(u[r]).
// ---------------------------------------------------------------------------
template <bool FIRST, bool LAST>
__global__ __launch_bounds__(256) void sink_layer(
    const float* __restrict__ C, half_t* __restrict__ E,
    const float* __restrict__ v, const float* __restrict__ alpha,
    const float* __restrict__ d_eps, float* __restrict__ u,
    float* __restrict__ partial, float* __restrict__ out)
{
    const int b = blockIdx.x;
    const int t = threadIdx.x;
    const int wave = t >> 6;
    const int lane = t & 63;
    const int row0 = b * RPC;
    const float eps = d_eps[0];
    const float inv_eps = 1.0f / eps;

    __shared__ float v_s[NB];       // 32 KiB
    __shared__ float u_s[RPC];

    if (!FIRST) {
        const float4_t* vv = (const float4_t*)v;
        float4_t* vs4 = (float4_t*)v_s;
#pragma unroll
        for (int k = 0; k < 8; ++k) vs4[k * 256 + t] = vv[k * 256 + t];
        __syncthreads();
    }

    // ---- phase A: one row per wave-iteration (4 rows per wave) ----
#pragma unroll
    for (int rr = 0; rr < RPC / 4; ++rr) {
        const int r = row0 + wave * (RPC / 4) + rr;
        float acc = 0.0f;
        if (FIRST) {
            const float4_t* Crow = (const float4_t*)(C + (size_t)r * NB);
            half8_t* Erow = (half8_t*)(E + (size_t)r * NB);
#pragma unroll 2
            for (int k = 0; k < 16; ++k) {
                const int g = k * 64 + lane;        // half8 group, 1024/row
                float4_t c0 = Crow[2 * g], c1 = Crow[2 * g + 1];
                float e0 = __expf(-c0.x * inv_eps), e1 = __expf(-c0.y * inv_eps);
                float e2 = __expf(-c0.z * inv_eps), e3 = __expf(-c0.w * inv_eps);
                float e4 = __expf(-c1.x * inv_eps), e5 = __expf(-c1.y * inv_eps);
                float e6 = __expf(-c1.z * inv_eps), e7 = __expf(-c1.w * inv_eps);
                half8_t h;
                h[0] = (_Float16)e0; h[1] = (_Float16)e1;
                h[2] = (_Float16)e2; h[3] = (_Float16)e3;
                h[4] = (_Float16)e4; h[5] = (_Float16)e5;
                h[6] = (_Float16)e6; h[7] = (_Float16)e7;
                Erow[g] = h;
                acc += ((e0 + e1) + (e2 + e3)) + ((e4 + e5) + (e6 + e7));
            }
        } else {
            const half8_t* Erow = (const half8_t*)E + (size_t)r * (NB / 8);
            const float4_t* vs4 = (const float4_t*)v_s;
#pragma unroll 4
            for (int k = 0; k < 16; ++k) {
                const int g = k * 64 + lane;
                half8_t e = Erow[g];
                acc += dot8(e, vs4[2 * g], vs4[2 * g + 1]);
            }
        }
        acc = wave_sum(acc);
        if (lane == 0) {
            const float uu = alpha[r] / acc;
            u_s[r - row0] = uu;
            u[r] = uu;
            if (LAST) out[r] = eps * __logf(uu);
        }
    }
    __syncthreads();

    // ---- phase B: chunk colsums, E re-read (cache-hot) ----
    const half8_t* Eb = (const half8_t*)E;
#pragma unroll
    for (int cc = 0; cc < 4; ++cc) {
        const int g = cc * 256 + t;                 // half8 group within row
        float a[8];
#pragma unroll
        for (int k = 0; k < 8; ++k) a[k] = 0.0f;
#pragma unroll
        for (int r = 0; r < RPC; ++r) {
            const float ur = u_s[r];
            half8_t e = Eb[(size_t)(row0 + r) * (NB / 8) + g];
#pragma unroll
            for (int k = 0; k < 8; ++k) a[k] += ur * (float)e[k];
        }
        float4_t o0 = {a[0], a[1], a[2], a[3]};
        float4_t o1 = {a[4], a[5], a[6], a[7]};
        float4_t* p = (float4_t*)(partial + (size_t)b * NB + (size_t)g * 8);
        p[0] = o0;
        p[1] = o1;
    }
}

// ---------------------------------------------------------------------------
// Combine: v[j] = beta[j] / sum_ch partial[ch][j].
// Grid 128 x 256: block owns 64 cols; wave w sums chunks [w*128, (w+1)*128).
// LAST also writes out[NA+j] = eps*log(v[j]).
// ---------------------------------------------------------------------------
template <bool LAST>
__global__ __launch_bounds__(256) void sink_combine(
    const float* __restrict__ partial, const float* __restrict__ beta,
    const float* __restrict__ d_eps, float* __restrict__ v,
    float* __restrict__ out)
{
    const int lane = threadIdx.x & 63;
    const int w = threadIdx.x >> 6;
    const int col = blockIdx.x * 64 + lane;
    float s = 0.0f;
#pragma unroll 8
    for (int ch = w * (N_CH / 4); ch < (w + 1) * (N_CH / 4); ++ch)
        s += partial[(size_t)ch * NB + col];
    __shared__ float red[4][64];
    red[w][lane] = s;
    __syncthreads();
    if (w == 0) {
        const float tot = (red[0][lane] + red[1][lane]) +
                          (red[2][lane] + red[3][lane]);
        const float vv = beta[col] / tot;
        v[col] = vv;
        if (LAST) out[NA + col] = d_eps[0] * __logf(vv);
    }
}

// ===========================================================================
// Fallback path (ws too small for E): fp32 multi-kernel (round-3 style).
// ===========================================================================
__global__ __launch_bounds__(256) void fb_u_step(
    const float* __restrict__ C, const float* __restrict__ v,
    const float* __restrict__ alpha, const float* __restrict__ d_eps,
    float* __restrict__ u, int first)
{
    const int row = blockIdx.x;
    const int t = threadIdx.x;
    const float inv_eps = 1.0f / d_eps[0];
    const float4_t* Crow = (const float4_t*)(C + (size_t)row * NB);
    const float4_t* vv = (const float4_t*)v;
    float s = 0.0f;
#pragma unroll
    for (int k = 0; k < 8; ++k) {
        const int g = k * 256 + t;
        float4_t c = Crow[g];
        float4_t w = first ? float4_t{1.f, 1.f, 1.f, 1.f} : vv[g];
        s += __expf(-c.x * inv_eps) * w.x + __expf(-c.y * inv_eps) * w.y +
             __expf(-c.z * inv_eps) * w.z + __expf(-c.w * inv_eps) * w.w;
    }
    __shared__ float sm[256];
    sm[t] = s;
    __syncthreads();
    for (int off = 128; off > 0; off >>= 1) {
        if (t < off) sm[t] += sm[t + off];
        __syncthreads();
    }
    if (t == 0) u[row] = alpha[row] / sm[0];
}

__global__ __launch_bounds__(256) void fb_v_partial(
    const float* __restrict__ C, const float* __restrict__ u,
    const float* __restrict__ d_eps, float* __restrict__ partial)
{
    const int cc = blockIdx.x;
    const int rc = blockIdx.y;
    const int t = threadIdx.x;
    const int row0 = rc * FB_RPC;
    const float inv_eps = 1.0f / d_eps[0];
    const float4_t* Cb = (const float4_t*)C;
    const int g = (cc * 256 + t) * 2;
    float acc[8];
#pragma unroll
    for (int k = 0; k < 8; ++k) acc[k] = 0.0f;
#pragma unroll 4
    for (int r = 0; r < FB_RPC; ++r) {
        const float ur = u[row0 + r];
        float4_t c0 = Cb[(size_t)(row0 + r) * (NB / 4) + g];
        float4_t c1 = Cb[(size_t)(row0 + r) * (NB / 4) + g + 1];
        acc[0] += ur * __expf(-c0.x * inv_eps);
        acc[1] += ur * __expf(-c0.y * inv_eps);
        acc[2] += ur * __expf(-c0.z * inv_eps);
        acc[3] += ur * __expf(-c0.w * inv_eps);
        acc[4] += ur * __expf(-c1.x * inv_eps);
        acc[5] += ur * __expf(-c1.y * inv_eps);
        acc[6] += ur * __expf(-c1.z * inv_eps);
        acc[7] += ur * __expf(-c1.w * inv_eps);
    }
    float4_t o0 = {acc[0], acc[1], acc[2], acc[3]};
    float4_t o1 = {acc[4], acc[5], acc[6], acc[7]};
    float4_t* p = (float4_t*)(partial + (size_t)rc * NB + (size_t)(cc * 256 + t) * 8);
    p[0] = o0;
    p[1] = o1;
}

__global__ __launch_bounds__(256) void fb_v_combine(
    const float* __restrict__ partial, const float* __restrict__ beta,
    float* __restrict__ v)
{
    const int col = blockIdx.x * 256 + threadIdx.x;
    float s = 0.0f;
#pragma unroll 8
    for (int rc = 0; rc < FB_NCH; ++rc) s += partial[(size_t)rc * NB + col];
    v[col] = beta[col] / s;
}

__global__ __launch_bounds__(256) void fb_finalize(
    const float* __restrict__ u, const float* __restrict__ v,
    const float* __restrict__ d_eps, float* __restrict__ out)
{
    const int i = blockIdx.x * 256 + threadIdx.x;
    const float eps = d_eps[0];
    if (i < NA) out[i] = eps * logf(u[i]);
    else if (i < NA + NB) out[i] = eps * logf(v[i - NA]);
}

extern "C" void kernel_launch(void* const* d_in, const int* in_sizes, int n_in,
                              void* d_out, int out_size, void* d_ws, size_t ws_size,
                              hipStream_t stream)
{
    const float* alpha = (const float*)d_in[0];
    const float* beta  = (const float*)d_in[1];
    const float* C     = (const float*)d_in[2];
    const float* d_eps = (const float*)d_in[3];
    float* out = (float*)d_out;

    const size_t eBytes = (size_t)NA * NB * sizeof(half_t);    // 128 MiB
    const size_t pBytes = (size_t)N_CH * NB * sizeof(float);   // 16 MiB
    const size_t vecBytes = (size_t)NA * sizeof(float);        // 32 KiB

    char* ws = (char*)d_ws;
    const bool useE = ws_size >= eBytes + pBytes + 2 * vecBytes;

    const dim3 blk(256);

    if (useE) {
        half_t* E = (half_t*)ws;
        float* partial = (float*)(ws + eBytes);
        float* u = (float*)(ws + eBytes + pBytes);
        float* v = (float*)(ws + eBytes + pBytes + vecBytes);

        for (int layer = 0; layer < N_LAYERS; ++layer) {
            const bool last = (layer == N_LAYERS - 1);
            if (layer == 0)
                sink_layer<true, false><<<dim3(N_CH), blk, 0, stream>>>(
                    C, E, v, alpha, d_eps, u, partial, out);
            else if (!last)
                sink_layer<false, false><<<dim3(N_CH), blk, 0, stream>>>(
                    C, E, v, alpha, d_eps, u, partial, out);
            else
                sink_layer<false, true><<<dim3(N_CH), blk, 0, stream>>>(
                    C, E, v, alpha, d_eps, u, partial, out);

            if (!last)
                sink_combine<false><<<dim3(NB / 64), blk, 0, stream>>>(
                    partial, beta, d_eps, v, out);
            else
                sink_combine<true><<<dim3(NB / 64), blk, 0, stream>>>(
                    partial, beta, d_eps, v, out);
        }
    } else {
        const size_t fbPBytes = (size_t)FB_NCH * NB * sizeof(float);  // 4 MiB
        float* partial = (float*)ws;
        float* u = (float*)(ws + fbPBytes);
        float* v = (float*)(ws + fbPBytes + vecBytes);
        const dim3 gridRow(NA);
        const dim3 gridVP(NB / 2048, FB_NCH);
        for (int layer = 0; layer < N_LAYERS; ++layer) {
            fb_u_step<<<gridRow, blk, 0, stream>>>(C, v, alpha, d_eps, u,
                                                   layer == 0 ? 1 : 0);
            fb_v_partial<<<gridVP, blk, 0, stream>>>(C, u, d_eps, partial);
            fb_v_combine<<<dim3(NB / 256), blk, 0, stream>>>(partial, beta, v);
        }
        fb_finalize<<<dim3((NA + NB) / 256), blk, 0, stream>>>(u, v, d_eps, out);
    }
}